// Round 20
// baseline (193.288 us; speedup 1.0000x reference)
//
#include <hip/hip_runtime.h>
#include <math.h>

#define T_LEN 1024
#define VV 512
#define BB 64
#define NB 16
#define ANG_STEP 0.006135923151542565f   // 2*pi/1024
#define FADE_S 487
#define FADE_E 537

typedef float v2f __attribute__((ext_vector_type(2)));   // native vec for nontemporal stores

__device__ constexpr int KB[NB] = {1,2,3,4,5,6,7,8,12,16,24,32,48,64,96,128};
// cos/sin(2*pi*k/1024) rotation-step constants (R1/R6-verified)
__device__ constexpr float CWT[NB] = {
    0.9999811753f, 0.9999247018f, 0.9998305818f, 0.9996988187f,
    0.9995294175f, 0.9993223846f, 0.9990777278f, 0.9987954562f,
    0.9972904567f, 0.9951847267f, 0.9891765100f, 0.9807852804f,
    0.9569403357f, 0.9238795325f, 0.8314696123f, 0.7071067812f};
__device__ constexpr float SWT[NB] = {
    0.0061358846f, 0.0122715383f, 0.0184067299f, 0.0245412285f,
    0.0306748032f, 0.0368072229f, 0.0429382569f, 0.0490676743f,
    0.0735645636f, 0.0980171403f, 0.1467304745f, 0.1950903220f,
    0.2902846773f, 0.3826834324f, 0.5555702330f, 0.7071067812f};

// ---------------- Fused kernel v6: 16 waves/block (4 waves/SIMD) ----------------
// grid (BB, 4) = 256 blocks (1/CU), block 1024 = 16 waves. Wave w owns t-rows
// [w*64, w*64+64) of the block's 128-v slice (lane owns v0 = lane*2, VPT=2).
// cs in registers via rotation recurrence (no LDS table: VALU 27us/phase beats
// the per-byte LDS-pipe 41us/phase). R19's 2 waves/SIMD -> 4 here: idle filled.
// Reduction: 4 rounds through stride-9 scr (conflict-free-ish); H -> LDS HB
// (phase 2 reads it locally) + global Hg (for k_fixup).
__global__ __launch_bounds__(1024) void k_fused(const float* __restrict__ x,
                                                const float* __restrict__ ger,
                                                const float* __restrict__ gei,
                                                const float* __restrict__ glr,
                                                const float* __restrict__ gli,
                                                float* __restrict__ Hg,
                                                float* __restrict__ out) {
    const int b    = blockIdx.x;
    const int vc   = blockIdx.y;
    const int tid  = threadIdx.x;
    const int wave = tid >> 6;           // 0..15
    const int lane = tid & 63;

    __shared__ __align__(16) float scr[8 * 128 * 9];   // 36 KB reduction scratch (stride 9)
    __shared__ __align__(16) float HB[64 * 128];       // 32 KB block-local H

    const int trow = wave * 64;
    const int v0   = lane * 2;
    const float2* xrd = (const float2*)(x + ((size_t)b * T_LEN + trow) * VV + vc * 128) + lane;

    // ---- phase 1: per-wave DFT over its 64 t rows (recurrence cs) ----
    float ar0[NB], ai0[NB], ar1[NB], ai1[NB], c[NB], s[NB];
#pragma unroll
    for (int j = 0; j < NB; ++j) {
        ar0[j] = ai0[j] = ar1[j] = ai1[j] = 0.f;
        int n0 = (KB[j] * trow) & (T_LEN - 1);
        sincosf(ANG_STEP * (float)n0, &s[j], &c[j]);
    }

#define DFT_STEP(AV)                                            \
    do {                                                        \
        _Pragma("unroll")                                       \
        for (int j = 0; j < NB; ++j) {                          \
            ar0[j] = fmaf((AV).x, c[j], ar0[j]);                \
            ai0[j] = fmaf(-(AV).x, s[j], ai0[j]);               \
            ar1[j] = fmaf((AV).y, c[j], ar1[j]);                \
            ai1[j] = fmaf(-(AV).y, s[j], ai1[j]);               \
            float cn = fmaf(c[j], CWT[j], -(s[j] * SWT[j]));    \
            float sn = fmaf(s[j], CWT[j], c[j] * SWT[j]);       \
            c[j] = cn; s[j] = sn;                               \
        }                                                       \
    } while (0)

    {
        float2 a0 = xrd[(size_t)0 * 256];
        float2 a1 = xrd[(size_t)1 * 256];
        float2 a2 = xrd[(size_t)2 * 256];
        float2 a3 = xrd[(size_t)3 * 256];
#pragma unroll 1
        for (int i = 0; i < 60; i += 4) {
            float2 b0 = xrd[(size_t)(i + 4) * 256];
            float2 b1 = xrd[(size_t)(i + 5) * 256];
            float2 b2 = xrd[(size_t)(i + 6) * 256];
            float2 b3 = xrd[(size_t)(i + 7) * 256];
            DFT_STEP(a0); DFT_STEP(a1); DFT_STEP(a2); DFT_STEP(a3);
            a0 = b0; a1 = b1; a2 = b2; a3 = b3;
        }
        DFT_STEP(a0); DFT_STEP(a1); DFT_STEP(a2); DFT_STEP(a3);
    }
#undef DFT_STEP

    // ---- reduction: 4 rounds of 8 bins; 16 wave-partials -> 8 (RMW) -> sum ----
    float Xre_lo, Xre_hi, Xim_lo, Xim_hi;
    const int vq = tid >> 3;             // 0..127
    const int jq = tid & 7;              // 0..7

#define RED_ROUND(SRC0, SRC1, JOFF, DST)                                         \
    do {                                                                         \
        if (wave < 8) {                                                          \
            _Pragma("unroll")                                                    \
            for (int jj = 0; jj < 8; ++jj) {                                     \
                scr[((size_t)wave * 128 + v0)     * 9 + jj] = SRC0[(JOFF) + jj]; \
                scr[((size_t)wave * 128 + v0 + 1) * 9 + jj] = SRC1[(JOFF) + jj]; \
            }                                                                    \
        }                                                                        \
        __syncthreads();                                                         \
        if (wave >= 8) {                                                         \
            const int w2 = wave - 8;                                             \
            _Pragma("unroll")                                                    \
            for (int jj = 0; jj < 8; ++jj) {                                     \
                scr[((size_t)w2 * 128 + v0)     * 9 + jj] += SRC0[(JOFF) + jj];  \
                scr[((size_t)w2 * 128 + v0 + 1) * 9 + jj] += SRC1[(JOFF) + jj];  \
            }                                                                    \
        }                                                                        \
        __syncthreads();                                                         \
        {                                                                        \
            float acc = 0.f;                                                     \
            _Pragma("unroll")                                                    \
            for (int w = 0; w < 8; ++w)                                          \
                acc += scr[((size_t)w * 128 + vq) * 9 + jq];                     \
            DST = acc;                                                           \
        }                                                                        \
        __syncthreads();                                                         \
    } while (0)

    RED_ROUND(ar0, ar1, 0, Xre_lo);
    RED_ROUND(ar0, ar1, 8, Xre_hi);
    RED_ROUND(ai0, ai1, 0, Xim_lo);
    RED_ROUND(ai0, ai1, 8, Xim_hi);
#undef RED_ROUND

    // ---- H compute -> LDS HB + global Hg (2 j-cells per thread, v=vq) ----
    const float scale = 2.0f / (float)T_LEN;
    {
        float* hg = Hg + (size_t)b * 64 * VV;
        const int vg = vc * 128 + vq;
#pragma unroll
        for (int half = 0; half < 2; ++half) {
            const int jc = jq + half * 8;
            const float Xr = half ? Xre_hi : Xre_lo;
            const float Xi = half ? Xim_hi : Xim_lo;
            float er = ger[vg * NB + jc], ei = gei[vg * NB + jc];
            float lr = glr[vg * NB + jc], li = gli[vg * NB + jc];
            float here  = (Xr * er - Xi * ei) * scale;
            float heimN = -(Xr * ei + Xi * er) * scale;
            float hlre  = (Xr * lr - Xi * li) * scale;
            float hlimN = -(Xr * li + Xi * lr) * scale;
            HB[jc * 128 + vq]        = here;
            HB[(16 + jc) * 128 + vq] = heimN;
            HB[(32 + jc) * 128 + vq] = hlre;
            HB[(48 + jc) * 128 + vq] = hlimN;
            hg[(size_t)jc * VV + vg]        = here;
            hg[(size_t)(16 + jc) * VV + vg] = heimN;
            hg[(size_t)(32 + jc) * VV + vg] = hlre;
            hg[(size_t)(48 + jc) * VV + vg] = hlimN;
        }
    }
    __syncthreads();   // HB visible before phase-2 reads

    // ---- phase 2: apply (He waves 0..7, Hl waves 8..15), recurrence cs ----
    float hr0[NB], hi0[NB], hr1[NB], hi1[NB];
    {
        const int qb = (wave < 8) ? 0 : 32;
#pragma unroll
        for (int j = 0; j < NB; ++j) {
            hr0[j] = HB[(qb + j) * 128 + v0];
            hr1[j] = HB[(qb + j) * 128 + v0 + 1];
            hi0[j] = HB[(qb + 16 + j) * 128 + v0];
            hi1[j] = HB[(qb + 16 + j) * 128 + v0 + 1];
        }
#pragma unroll
        for (int j = 0; j < NB; ++j) {
            int n0 = (KB[j] * trow) & (T_LEN - 1);
            sincosf(ANG_STEP * (float)n0, &s[j], &c[j]);
        }
    }

    v2f* ow = (v2f*)(out + ((size_t)b * T_LEN + trow) * VV + vc * 128) + lane;

#define APPLY_STEP(TT, AV)                                      \
    do {                                                        \
        float s0 = 0.f, s1 = 0.f;                               \
        _Pragma("unroll")                                       \
        for (int j = 0; j < NB; ++j) {                          \
            s0 = fmaf(hr0[j], c[j], s0);                        \
            s0 = fmaf(hi0[j], s[j], s0);                        \
            s1 = fmaf(hr1[j], c[j], s1);                        \
            s1 = fmaf(hi1[j], s[j], s1);                        \
            float cn = fmaf(c[j], CWT[j], -(s[j] * SWT[j]));    \
            float sn = fmaf(s[j], CWT[j], c[j] * SWT[j]);       \
            c[j] = cn; s[j] = sn;                               \
        }                                                       \
        v2f ov; ov.x = (AV).x + s0; ov.y = (AV).y + s1;         \
        __builtin_nontemporal_store(ov, &ow[(size_t)(TT) * 256]); \
    } while (0)

    {
        float2 a0 = xrd[(size_t)0 * 256];
        float2 a1 = xrd[(size_t)1 * 256];
        float2 a2 = xrd[(size_t)2 * 256];
        float2 a3 = xrd[(size_t)3 * 256];
#pragma unroll 1
        for (int i = 0; i < 60; i += 4) {
            float2 b0 = xrd[(size_t)(i + 4) * 256];
            float2 b1 = xrd[(size_t)(i + 5) * 256];
            float2 b2 = xrd[(size_t)(i + 6) * 256];
            float2 b3 = xrd[(size_t)(i + 7) * 256];
            APPLY_STEP(i + 0, a0); APPLY_STEP(i + 1, a1);
            APPLY_STEP(i + 2, a2); APPLY_STEP(i + 3, a3);
            a0 = b0; a1 = b1; a2 = b2; a3 = b3;
        }
        APPLY_STEP(60, a0); APPLY_STEP(61, a1);
        APPLY_STEP(62, a2); APPLY_STEP(63, a3);
    }
#undef APPLY_STEP
}

// ---------------- Fade fixup, rows 487..536 only (exact dual-H crossfade) ----------------
// grid (BB, 2), block 512, thread owns v = tid.
__global__ __launch_bounds__(512) void k_fixup(const float* __restrict__ x,
                                               const float* __restrict__ H,
                                               float* __restrict__ out) {
    const int b   = blockIdx.x;
    const int tz  = blockIdx.y;
    const int tid = threadIdx.x;
    const int ts  = tz ? 512 : FADE_S;
    const int te  = tz ? FADE_E : 512;
    const int nt  = te - ts;                   // 25 rows each

    __shared__ float2 tab[32][NB];
    for (int i = tid; i < nt * NB; i += 512) {
        int t = i >> 4, j = i & 15;
        int idx = (KB[j] * (ts + t)) & (T_LEN - 1);
        float ss, cc; sincosf(ANG_STEP * (float)idx, &ss, &cc);
        tab[t][j] = make_float2(cc, ss);
    }

    float er[NB], ei[NB], lr[NB], li[NB];
    const float* hp = H + (size_t)b * 64 * VV + tid;
#pragma unroll
    for (int j = 0; j < NB; ++j) {
        er[j] = hp[(size_t)j        * VV];
        ei[j] = hp[(size_t)(16 + j) * VV];
        lr[j] = hp[(size_t)(32 + j) * VV];
        li[j] = hp[(size_t)(48 + j) * VV];
    }
    __syncthreads();

    const float* xrd = x + ((size_t)b * T_LEN + ts) * VV + tid;
    float*       ow  = out + ((size_t)b * T_LEN + ts) * VV + tid;

    for (int t = 0; t < nt; ++t) {
        float av = xrd[(size_t)t * VV];
        const int tg = ts + t;
        float se = 0.f, sl = 0.f;
#pragma unroll
        for (int j = 0; j < NB; ++j) {
            float2 cs = tab[t][j];
            se = fmaf(er[j], cs.x, se); se = fmaf(ei[j], cs.y, se);
            sl = fmaf(lr[j], cs.x, sl); sl = fmaf(li[j], cs.y, sl);
        }
        float w = 1.0f - (float)(tg - FADE_S) * (1.0f / 50.0f);
        ow[(size_t)t * VV] = av + fmaf(w, se - sl, sl);
    }
}

extern "C" void kernel_launch(void* const* d_in, const int* in_sizes, int n_in,
                              void* d_out, int out_size, void* d_ws, size_t ws_size,
                              hipStream_t stream) {
    (void)in_sizes; (void)n_in; (void)out_size; (void)ws_size;
    const float* x   = (const float*)d_in[0];
    const float* ger = (const float*)d_in[1];
    const float* gei = (const float*)d_in[2];
    const float* glr = (const float*)d_in[3];
    const float* gli = (const float*)d_in[4];
    float* out = (float*)d_out;

    float* Hg = (float*)d_ws;    // BB*64*VV floats = 8.4 MB

    k_fused<<<dim3(BB, 4), 1024, 0, stream>>>(x, ger, gei, glr, gli, Hg, out);
    k_fixup<<<dim3(BB, 2), 512, 0, stream>>>(x, Hg, out);
}

// Round 21
// 191.788 us; speedup vs baseline: 1.0078x; 1.0078x over previous
//
#include <hip/hip_runtime.h>
#include <math.h>

#define T_LEN 1024
#define VV 512
#define BB 64
#define NB 16
#define ANG_STEP 0.006135923151542565f   // 2*pi/1024
#define FADE_S 487
#define FADE_E 537

typedef float v2f __attribute__((ext_vector_type(2)));   // native vec for nontemporal stores

__device__ constexpr int KB[NB] = {1,2,3,4,5,6,7,8,12,16,24,32,48,64,96,128};
// cos/sin(2*pi*k/1024) rotation-step constants (R1/R6-verified)
__device__ constexpr float CWT[NB] = {
    0.9999811753f, 0.9999247018f, 0.9998305818f, 0.9996988187f,
    0.9995294175f, 0.9993223846f, 0.9990777278f, 0.9987954562f,
    0.9972904567f, 0.9951847267f, 0.9891765100f, 0.9807852804f,
    0.9569403357f, 0.9238795325f, 0.8314696123f, 0.7071067812f};
__device__ constexpr float SWT[NB] = {
    0.0061358846f, 0.0122715383f, 0.0184067299f, 0.0245412285f,
    0.0306748032f, 0.0368072229f, 0.0429382569f, 0.0490676743f,
    0.0735645636f, 0.0980171403f, 0.1467304745f, 0.1950903220f,
    0.2902846773f, 0.3826834324f, 0.5555702330f, 0.7071067812f};

// ---------------- Fused kernel v7: 16 waves/block at VGPR=128 ----------------
// grid (BB, 4) = 256 blocks (1/CU), block 1024 = 16 waves (4 waves/EU). Wave w
// owns t-rows [w*64, w*64+64) of the block's 128-v slice (lane v0=lane*2, VPT=2).
// __launch_bounds__(1024, 4): min 4 waves/EU -> VGPR cap 128 (live ~114, no
// spill). R20's bare (1024) defaulted to 64 VGPR -> 330 MB scratch traffic.
// cs in registers via rotation recurrence; reduction via stride-9 scr; H -> LDS
// HB (local phase-2 reads) + global Hg (for k_fixup).
__global__ __launch_bounds__(1024, 4) void k_fused(const float* __restrict__ x,
                                                   const float* __restrict__ ger,
                                                   const float* __restrict__ gei,
                                                   const float* __restrict__ glr,
                                                   const float* __restrict__ gli,
                                                   float* __restrict__ Hg,
                                                   float* __restrict__ out) {
    const int b    = blockIdx.x;
    const int vc   = blockIdx.y;
    const int tid  = threadIdx.x;
    const int wave = tid >> 6;           // 0..15
    const int lane = tid & 63;

    __shared__ __align__(16) float scr[8 * 128 * 9];   // 36 KB reduction scratch (stride 9)
    __shared__ __align__(16) float HB[64 * 128];       // 32 KB block-local H

    const int trow = wave * 64;
    const int v0   = lane * 2;
    const float2* xrd = (const float2*)(x + ((size_t)b * T_LEN + trow) * VV + vc * 128) + lane;

    // ---- phase 1: per-wave DFT over its 64 t rows (recurrence cs) ----
    float ar0[NB], ai0[NB], ar1[NB], ai1[NB], c[NB], s[NB];
#pragma unroll
    for (int j = 0; j < NB; ++j) {
        ar0[j] = ai0[j] = ar1[j] = ai1[j] = 0.f;
        int n0 = (KB[j] * trow) & (T_LEN - 1);
        sincosf(ANG_STEP * (float)n0, &s[j], &c[j]);
    }

#define DFT_STEP(AV)                                            \
    do {                                                        \
        _Pragma("unroll")                                       \
        for (int j = 0; j < NB; ++j) {                          \
            ar0[j] = fmaf((AV).x, c[j], ar0[j]);                \
            ai0[j] = fmaf(-(AV).x, s[j], ai0[j]);               \
            ar1[j] = fmaf((AV).y, c[j], ar1[j]);                \
            ai1[j] = fmaf(-(AV).y, s[j], ai1[j]);               \
            float cn = fmaf(c[j], CWT[j], -(s[j] * SWT[j]));    \
            float sn = fmaf(s[j], CWT[j], c[j] * SWT[j]);       \
            c[j] = cn; s[j] = sn;                               \
        }                                                       \
    } while (0)

    {
        float2 a0 = xrd[(size_t)0 * 256];
        float2 a1 = xrd[(size_t)1 * 256];
        float2 a2 = xrd[(size_t)2 * 256];
        float2 a3 = xrd[(size_t)3 * 256];
#pragma unroll 1
        for (int i = 0; i < 60; i += 4) {
            float2 b0 = xrd[(size_t)(i + 4) * 256];
            float2 b1 = xrd[(size_t)(i + 5) * 256];
            float2 b2 = xrd[(size_t)(i + 6) * 256];
            float2 b3 = xrd[(size_t)(i + 7) * 256];
            DFT_STEP(a0); DFT_STEP(a1); DFT_STEP(a2); DFT_STEP(a3);
            a0 = b0; a1 = b1; a2 = b2; a3 = b3;
        }
        DFT_STEP(a0); DFT_STEP(a1); DFT_STEP(a2); DFT_STEP(a3);
    }
#undef DFT_STEP

    // ---- reduction: 4 rounds of 8 bins; 16 wave-partials -> 8 (RMW) -> sum ----
    float Xre_lo, Xre_hi, Xim_lo, Xim_hi;
    const int vq = tid >> 3;             // 0..127
    const int jq = tid & 7;              // 0..7

#define RED_ROUND(SRC0, SRC1, JOFF, DST)                                         \
    do {                                                                         \
        if (wave < 8) {                                                          \
            _Pragma("unroll")                                                    \
            for (int jj = 0; jj < 8; ++jj) {                                     \
                scr[((size_t)wave * 128 + v0)     * 9 + jj] = SRC0[(JOFF) + jj]; \
                scr[((size_t)wave * 128 + v0 + 1) * 9 + jj] = SRC1[(JOFF) + jj]; \
            }                                                                    \
        }                                                                        \
        __syncthreads();                                                         \
        if (wave >= 8) {                                                         \
            const int w2 = wave - 8;                                             \
            _Pragma("unroll")                                                    \
            for (int jj = 0; jj < 8; ++jj) {                                     \
                scr[((size_t)w2 * 128 + v0)     * 9 + jj] += SRC0[(JOFF) + jj];  \
                scr[((size_t)w2 * 128 + v0 + 1) * 9 + jj] += SRC1[(JOFF) + jj];  \
            }                                                                    \
        }                                                                        \
        __syncthreads();                                                         \
        {                                                                        \
            float acc = 0.f;                                                     \
            _Pragma("unroll")                                                    \
            for (int w = 0; w < 8; ++w)                                          \
                acc += scr[((size_t)w * 128 + vq) * 9 + jq];                     \
            DST = acc;                                                           \
        }                                                                        \
        __syncthreads();                                                         \
    } while (0)

    RED_ROUND(ar0, ar1, 0, Xre_lo);
    RED_ROUND(ar0, ar1, 8, Xre_hi);
    RED_ROUND(ai0, ai1, 0, Xim_lo);
    RED_ROUND(ai0, ai1, 8, Xim_hi);
#undef RED_ROUND

    // ---- H compute -> LDS HB + global Hg (2 j-cells per thread, v=vq) ----
    const float scale = 2.0f / (float)T_LEN;
    {
        float* hg = Hg + (size_t)b * 64 * VV;
        const int vg = vc * 128 + vq;
#pragma unroll
        for (int half = 0; half < 2; ++half) {
            const int jc = jq + half * 8;
            const float Xr = half ? Xre_hi : Xre_lo;
            const float Xi = half ? Xim_hi : Xim_lo;
            float er = ger[vg * NB + jc], ei = gei[vg * NB + jc];
            float lr = glr[vg * NB + jc], li = gli[vg * NB + jc];
            float here  = (Xr * er - Xi * ei) * scale;
            float heimN = -(Xr * ei + Xi * er) * scale;
            float hlre  = (Xr * lr - Xi * li) * scale;
            float hlimN = -(Xr * li + Xi * lr) * scale;
            HB[jc * 128 + vq]        = here;
            HB[(16 + jc) * 128 + vq] = heimN;
            HB[(32 + jc) * 128 + vq] = hlre;
            HB[(48 + jc) * 128 + vq] = hlimN;
            hg[(size_t)jc * VV + vg]        = here;
            hg[(size_t)(16 + jc) * VV + vg] = heimN;
            hg[(size_t)(32 + jc) * VV + vg] = hlre;
            hg[(size_t)(48 + jc) * VV + vg] = hlimN;
        }
    }
    __syncthreads();   // HB visible before phase-2 reads

    // ---- phase 2: apply (He waves 0..7, Hl waves 8..15), recurrence cs ----
    float hr0[NB], hi0[NB], hr1[NB], hi1[NB];
    {
        const int qb = (wave < 8) ? 0 : 32;
#pragma unroll
        for (int j = 0; j < NB; ++j) {
            hr0[j] = HB[(qb + j) * 128 + v0];
            hr1[j] = HB[(qb + j) * 128 + v0 + 1];
            hi0[j] = HB[(qb + 16 + j) * 128 + v0];
            hi1[j] = HB[(qb + 16 + j) * 128 + v0 + 1];
        }
#pragma unroll
        for (int j = 0; j < NB; ++j) {
            int n0 = (KB[j] * trow) & (T_LEN - 1);
            sincosf(ANG_STEP * (float)n0, &s[j], &c[j]);
        }
    }

    v2f* ow = (v2f*)(out + ((size_t)b * T_LEN + trow) * VV + vc * 128) + lane;

#define APPLY_STEP(TT, AV)                                      \
    do {                                                        \
        float s0 = 0.f, s1 = 0.f;                               \
        _Pragma("unroll")                                       \
        for (int j = 0; j < NB; ++j) {                          \
            s0 = fmaf(hr0[j], c[j], s0);                        \
            s0 = fmaf(hi0[j], s[j], s0);                        \
            s1 = fmaf(hr1[j], c[j], s1);                        \
            s1 = fmaf(hi1[j], s[j], s1);                        \
            float cn = fmaf(c[j], CWT[j], -(s[j] * SWT[j]));    \
            float sn = fmaf(s[j], CWT[j], c[j] * SWT[j]);       \
            c[j] = cn; s[j] = sn;                               \
        }                                                       \
        v2f ov; ov.x = (AV).x + s0; ov.y = (AV).y + s1;         \
        __builtin_nontemporal_store(ov, &ow[(size_t)(TT) * 256]); \
    } while (0)

    {
        float2 a0 = xrd[(size_t)0 * 256];
        float2 a1 = xrd[(size_t)1 * 256];
        float2 a2 = xrd[(size_t)2 * 256];
        float2 a3 = xrd[(size_t)3 * 256];
#pragma unroll 1
        for (int i = 0; i < 60; i += 4) {
            float2 b0 = xrd[(size_t)(i + 4) * 256];
            float2 b1 = xrd[(size_t)(i + 5) * 256];
            float2 b2 = xrd[(size_t)(i + 6) * 256];
            float2 b3 = xrd[(size_t)(i + 7) * 256];
            APPLY_STEP(i + 0, a0); APPLY_STEP(i + 1, a1);
            APPLY_STEP(i + 2, a2); APPLY_STEP(i + 3, a3);
            a0 = b0; a1 = b1; a2 = b2; a3 = b3;
        }
        APPLY_STEP(60, a0); APPLY_STEP(61, a1);
        APPLY_STEP(62, a2); APPLY_STEP(63, a3);
    }
#undef APPLY_STEP
}

// ---------------- Fade fixup, rows 487..536 only (exact dual-H crossfade) ----------------
// grid (BB, 2), block 512, thread owns v = tid.
__global__ __launch_bounds__(512) void k_fixup(const float* __restrict__ x,
                                               const float* __restrict__ H,
                                               float* __restrict__ out) {
    const int b   = blockIdx.x;
    const int tz  = blockIdx.y;
    const int tid = threadIdx.x;
    const int ts  = tz ? 512 : FADE_S;
    const int te  = tz ? FADE_E : 512;
    const int nt  = te - ts;                   // 25 rows each

    __shared__ float2 tab[32][NB];
    for (int i = tid; i < nt * NB; i += 512) {
        int t = i >> 4, j = i & 15;
        int idx = (KB[j] * (ts + t)) & (T_LEN - 1);
        float ss, cc; sincosf(ANG_STEP * (float)idx, &ss, &cc);
        tab[t][j] = make_float2(cc, ss);
    }

    float er[NB], ei[NB], lr[NB], li[NB];
    const float* hp = H + (size_t)b * 64 * VV + tid;
#pragma unroll
    for (int j = 0; j < NB; ++j) {
        er[j] = hp[(size_t)j        * VV];
        ei[j] = hp[(size_t)(16 + j) * VV];
        lr[j] = hp[(size_t)(32 + j) * VV];
        li[j] = hp[(size_t)(48 + j) * VV];
    }
    __syncthreads();

    const float* xrd = x + ((size_t)b * T_LEN + ts) * VV + tid;
    float*       ow  = out + ((size_t)b * T_LEN + ts) * VV + tid;

    for (int t = 0; t < nt; ++t) {
        float av = xrd[(size_t)t * VV];
        const int tg = ts + t;
        float se = 0.f, sl = 0.f;
#pragma unroll
        for (int j = 0; j < NB; ++j) {
            float2 cs = tab[t][j];
            se = fmaf(er[j], cs.x, se); se = fmaf(ei[j], cs.y, se);
            sl = fmaf(lr[j], cs.x, sl); sl = fmaf(li[j], cs.y, sl);
        }
        float w = 1.0f - (float)(tg - FADE_S) * (1.0f / 50.0f);
        ow[(size_t)t * VV] = av + fmaf(w, se - sl, sl);
    }
}

extern "C" void kernel_launch(void* const* d_in, const int* in_sizes, int n_in,
                              void* d_out, int out_size, void* d_ws, size_t ws_size,
                              hipStream_t stream) {
    (void)in_sizes; (void)n_in; (void)out_size; (void)ws_size;
    const float* x   = (const float*)d_in[0];
    const float* ger = (const float*)d_in[1];
    const float* gei = (const float*)d_in[2];
    const float* glr = (const float*)d_in[3];
    const float* gli = (const float*)d_in[4];
    float* out = (float*)d_out;

    float* Hg = (float*)d_ws;    // BB*64*VV floats = 8.4 MB

    k_fused<<<dim3(BB, 4), 1024, 0, stream>>>(x, ger, gei, glr, gli, Hg, out);
    k_fixup<<<dim3(BB, 2), 512, 0, stream>>>(x, Hg, out);
}

// Round 22
// 131.928 us; speedup vs baseline: 1.4651x; 1.4537x over previous
//
#include <hip/hip_runtime.h>
#include <math.h>

#define T_LEN 1024
#define VV 512
#define BB 64
#define NB 16
#define ANG_STEP 0.006135923151542565f   // 2*pi/1024
#define FADE_S 487
#define FADE_E 537

__device__ constexpr int KB[NB] = {1,2,3,4,5,6,7,8,12,16,24,32,48,64,96,128};
__device__ constexpr float CWT[NB] = {    // cos(2*pi*k/1024)
    0.9999811753f, 0.9999247018f, 0.9998305818f, 0.9996988187f,
    0.9995294175f, 0.9993223846f, 0.9990777278f, 0.9987954562f,
    0.9972904567f, 0.9951847267f, 0.9891765100f, 0.9807852804f,
    0.9569403357f, 0.9238795325f, 0.8314696123f, 0.7071067812f};
__device__ constexpr float SWT[NB] = {    // sin(2*pi*k/1024)
    0.0061358846f, 0.0122715383f, 0.0184067299f, 0.0245412285f,
    0.0306748032f, 0.0368072229f, 0.0429382569f, 0.0490676743f,
    0.0735645636f, 0.0980171403f, 0.1467304745f, 0.1950903220f,
    0.2902846773f, 0.3826834324f, 0.5555702330f, 0.7071067812f};
__device__ constexpr float C2W[NB] = {    // 2*cos(2*pi*k/1024) for Chebyshev step
    1.9999623506f, 1.9998494036f, 1.9996611636f, 1.9993976374f,
    1.9990588350f, 1.9986447692f, 1.9981554556f, 1.9975909124f,
    1.9945809134f, 1.9903694534f, 1.9783530200f, 1.9615705608f,
    1.9138806714f, 1.8477590650f, 1.6629392246f, 1.4142135624f};

// ---------------- Fused kernel v8: 2 blocks/CU, Chebyshev recurrence ----------------
// grid (BB, 8) = 512 blocks (2/CU -> 16 waves/CU = 4/SIMD), block 512 = 8 waves.
// Block owns a 64-v slice (lane owns v = vc*64 + lane, VPT=1); wave w owns t-rows
// [w*128, w*128+128). cs via 3-term Chebyshev (c_{n+1} = 2cosw*c_n - c_{n-1}):
// 2 fma/bin/step -> 64 inst per t-step for 64 v = 1 inst/elem (VPT=2 parity) at
// ~112 live regs (fits the 128-reg envelope 512-thr blocks reliably get).
// Reduction: re/im rounds through stride-17 scr (RMW waves 4..7). H -> LDS HB
// (phase-2 local) + global Hg (k_fixup). Fade rows overwritten by k_fixup.
__global__ __launch_bounds__(512) void k_fused(const float* __restrict__ x,
                                               const float* __restrict__ ger,
                                               const float* __restrict__ gei,
                                               const float* __restrict__ glr,
                                               const float* __restrict__ gli,
                                               float* __restrict__ Hg,
                                               float* __restrict__ out) {
    const int b    = blockIdx.x;
    const int vc   = blockIdx.y;          // 0..7, 64-v slice
    const int tid  = threadIdx.x;
    const int wave = tid >> 6;            // 0..7
    const int lane = tid & 63;            // v within slice

    __shared__ __align__(16) float scr[4 * 64 * 17];   // 17.4 KB reduction scratch
    __shared__ __align__(16) float HB[64 * 64];        // 16 KB block-local H

    const int trow = wave * 128;
    const float* xrd = x + ((size_t)b * T_LEN + trow) * VV + vc * 64 + lane;

    // ---- phase 1: per-wave DFT over its 128 t rows (Chebyshev cs) ----
    float ar[NB], ai[NB], c[NB], s[NB], cp[NB], sp[NB];
#pragma unroll
    for (int j = 0; j < NB; ++j) {
        ar[j] = ai[j] = 0.f;
        int n0 = (KB[j] * trow) & (T_LEN - 1);
        sincosf(ANG_STEP * (float)n0, &s[j], &c[j]);
        // previous sample (n0-1): rotate backward by w
        cp[j] = fmaf(c[j], CWT[j], s[j] * SWT[j]);
        sp[j] = fmaf(s[j], CWT[j], -(c[j] * SWT[j]));
    }

#define DFT_STEP(AV)                                           \
    do {                                                       \
        _Pragma("unroll")                                      \
        for (int j = 0; j < NB; ++j) {                         \
            ar[j] = fmaf((AV), c[j], ar[j]);                   \
            ai[j] = fmaf(-(AV), s[j], ai[j]);                  \
            float cn = fmaf(C2W[j], c[j], -cp[j]);             \
            float sn = fmaf(C2W[j], s[j], -sp[j]);             \
            cp[j] = c[j]; sp[j] = s[j]; c[j] = cn; s[j] = sn;  \
        }                                                      \
    } while (0)

    {
        float a0 = xrd[(size_t)0 * VV];
        float a1 = xrd[(size_t)1 * VV];
        float a2 = xrd[(size_t)2 * VV];
        float a3 = xrd[(size_t)3 * VV];
#pragma unroll 1
        for (int i = 0; i < 124; i += 4) {
            float b0 = xrd[(size_t)(i + 4) * VV];
            float b1 = xrd[(size_t)(i + 5) * VV];
            float b2 = xrd[(size_t)(i + 6) * VV];
            float b3 = xrd[(size_t)(i + 7) * VV];
            DFT_STEP(a0); DFT_STEP(a1); DFT_STEP(a2); DFT_STEP(a3);
            a0 = b0; a1 = b1; a2 = b2; a3 = b3;
        }
        DFT_STEP(a0); DFT_STEP(a1); DFT_STEP(a2); DFT_STEP(a3);
    }
#undef DFT_STEP

    // ---- reduction: 2 rounds (re, im); waves 0-3 write, 4-7 RMW; read 2 cells/thread ----
    float Xre[2], Xim[2];

    if (wave < 4) {
#pragma unroll
        for (int j = 0; j < NB; ++j)
            scr[((size_t)wave * 64 + lane) * 17 + j] = ar[j];
    }
    __syncthreads();
    if (wave >= 4) {
        const int w2 = wave - 4;
#pragma unroll
        for (int j = 0; j < NB; ++j)
            scr[((size_t)w2 * 64 + lane) * 17 + j] += ar[j];
    }
    __syncthreads();
#pragma unroll
    for (int q = 0; q < 2; ++q) {
        const int cc = tid * 2 + q;
        const int vq = cc >> 4, jq = cc & 15;
        Xre[q] = scr[((size_t)0 * 64 + vq) * 17 + jq]
               + scr[((size_t)1 * 64 + vq) * 17 + jq]
               + scr[((size_t)2 * 64 + vq) * 17 + jq]
               + scr[((size_t)3 * 64 + vq) * 17 + jq];
    }
    __syncthreads();

    if (wave < 4) {
#pragma unroll
        for (int j = 0; j < NB; ++j)
            scr[((size_t)wave * 64 + lane) * 17 + j] = ai[j];
    }
    __syncthreads();
    if (wave >= 4) {
        const int w2 = wave - 4;
#pragma unroll
        for (int j = 0; j < NB; ++j)
            scr[((size_t)w2 * 64 + lane) * 17 + j] += ai[j];
    }
    __syncthreads();
#pragma unroll
    for (int q = 0; q < 2; ++q) {
        const int cc = tid * 2 + q;
        const int vq = cc >> 4, jq = cc & 15;
        Xim[q] = scr[((size_t)0 * 64 + vq) * 17 + jq]
               + scr[((size_t)1 * 64 + vq) * 17 + jq]
               + scr[((size_t)2 * 64 + vq) * 17 + jq]
               + scr[((size_t)3 * 64 + vq) * 17 + jq];
    }

    // ---- H compute -> LDS HB + global Hg (2 cells per thread) ----
    const float scale = 2.0f / (float)T_LEN;
    {
        float* hg = Hg + (size_t)b * 64 * VV;
#pragma unroll
        for (int q = 0; q < 2; ++q) {
            const int cc = tid * 2 + q;
            const int vq = cc >> 4, jq = cc & 15;
            const int vg = vc * 64 + vq;
            float er = ger[vg * NB + jq], ei = gei[vg * NB + jq];
            float lr = glr[vg * NB + jq], li = gli[vg * NB + jq];
            float here  = (Xre[q] * er - Xim[q] * ei) * scale;
            float heimN = -(Xre[q] * ei + Xim[q] * er) * scale;
            float hlre  = (Xre[q] * lr - Xim[q] * li) * scale;
            float hlimN = -(Xre[q] * li + Xim[q] * lr) * scale;
            HB[jq * 64 + vq]        = here;
            HB[(16 + jq) * 64 + vq] = heimN;
            HB[(32 + jq) * 64 + vq] = hlre;
            HB[(48 + jq) * 64 + vq] = hlimN;
            hg[(size_t)jq * VV + vg]        = here;
            hg[(size_t)(16 + jq) * VV + vg] = heimN;
            hg[(size_t)(32 + jq) * VV + vg] = hlre;
            hg[(size_t)(48 + jq) * VV + vg] = hlimN;
        }
    }
    __syncthreads();   // HB visible before phase-2 reads

    // ---- phase 2: apply (He waves 0..3, Hl waves 4..7), Chebyshev cs ----
    float hr[NB], hi[NB];
    {
        const int qb = (wave < 4) ? 0 : 32;
#pragma unroll
        for (int j = 0; j < NB; ++j) {
            hr[j] = HB[(qb + j) * 64 + lane];
            hi[j] = HB[(qb + 16 + j) * 64 + lane];
        }
#pragma unroll
        for (int j = 0; j < NB; ++j) {
            int n0 = (KB[j] * trow) & (T_LEN - 1);
            sincosf(ANG_STEP * (float)n0, &s[j], &c[j]);
            cp[j] = fmaf(c[j], CWT[j], s[j] * SWT[j]);
            sp[j] = fmaf(s[j], CWT[j], -(c[j] * SWT[j]));
        }
    }

    float* ow = out + ((size_t)b * T_LEN + trow) * VV + vc * 64 + lane;

#define APPLY_STEP(TT, AV)                                     \
    do {                                                       \
        float s0 = 0.f;                                        \
        _Pragma("unroll")                                      \
        for (int j = 0; j < NB; ++j) {                         \
            s0 = fmaf(hr[j], c[j], s0);                        \
            s0 = fmaf(hi[j], s[j], s0);                        \
            float cn = fmaf(C2W[j], c[j], -cp[j]);             \
            float sn = fmaf(C2W[j], s[j], -sp[j]);             \
            cp[j] = c[j]; sp[j] = s[j]; c[j] = cn; s[j] = sn;  \
        }                                                      \
        __builtin_nontemporal_store((AV) + s0,                 \
            &ow[(size_t)(TT) * VV]);                           \
    } while (0)

    {
        float a0 = xrd[(size_t)0 * VV];
        float a1 = xrd[(size_t)1 * VV];
        float a2 = xrd[(size_t)2 * VV];
        float a3 = xrd[(size_t)3 * VV];
#pragma unroll 1
        for (int i = 0; i < 124; i += 4) {
            float b0 = xrd[(size_t)(i + 4) * VV];
            float b1 = xrd[(size_t)(i + 5) * VV];
            float b2 = xrd[(size_t)(i + 6) * VV];
            float b3 = xrd[(size_t)(i + 7) * VV];
            APPLY_STEP(i + 0, a0); APPLY_STEP(i + 1, a1);
            APPLY_STEP(i + 2, a2); APPLY_STEP(i + 3, a3);
            a0 = b0; a1 = b1; a2 = b2; a3 = b3;
        }
        APPLY_STEP(124, a0); APPLY_STEP(125, a1);
        APPLY_STEP(126, a2); APPLY_STEP(127, a3);
    }
#undef APPLY_STEP
}

// ---------------- Fade fixup, rows 487..536 only (exact dual-H crossfade) ----------------
// grid (BB, 2), block 512, thread owns v = tid.
__global__ __launch_bounds__(512) void k_fixup(const float* __restrict__ x,
                                               const float* __restrict__ H,
                                               float* __restrict__ out) {
    const int b   = blockIdx.x;
    const int tz  = blockIdx.y;
    const int tid = threadIdx.x;
    const int ts  = tz ? 512 : FADE_S;
    const int te  = tz ? FADE_E : 512;
    const int nt  = te - ts;                   // 25 rows each

    __shared__ float2 tab[32][NB];
    for (int i = tid; i < nt * NB; i += 512) {
        int t = i >> 4, j = i & 15;
        int idx = (KB[j] * (ts + t)) & (T_LEN - 1);
        float ss, cc; sincosf(ANG_STEP * (float)idx, &ss, &cc);
        tab[t][j] = make_float2(cc, ss);
    }

    float er[NB], ei[NB], lr[NB], li[NB];
    const float* hp = H + (size_t)b * 64 * VV + tid;
#pragma unroll
    for (int j = 0; j < NB; ++j) {
        er[j] = hp[(size_t)j        * VV];
        ei[j] = hp[(size_t)(16 + j) * VV];
        lr[j] = hp[(size_t)(32 + j) * VV];
        li[j] = hp[(size_t)(48 + j) * VV];
    }
    __syncthreads();

    const float* xrd = x + ((size_t)b * T_LEN + ts) * VV + tid;
    float*       ow  = out + ((size_t)b * T_LEN + ts) * VV + tid;

    for (int t = 0; t < nt; ++t) {
        float av = xrd[(size_t)t * VV];
        const int tg = ts + t;
        float se = 0.f, sl = 0.f;
#pragma unroll
        for (int j = 0; j < NB; ++j) {
            float2 cs = tab[t][j];
            se = fmaf(er[j], cs.x, se); se = fmaf(ei[j], cs.y, se);
            sl = fmaf(lr[j], cs.x, sl); sl = fmaf(li[j], cs.y, sl);
        }
        float w = 1.0f - (float)(tg - FADE_S) * (1.0f / 50.0f);
        ow[(size_t)t * VV] = av + fmaf(w, se - sl, sl);
    }
}

extern "C" void kernel_launch(void* const* d_in, const int* in_sizes, int n_in,
                              void* d_out, int out_size, void* d_ws, size_t ws_size,
                              hipStream_t stream) {
    (void)in_sizes; (void)n_in; (void)out_size; (void)ws_size;
    const float* x   = (const float*)d_in[0];
    const float* ger = (const float*)d_in[1];
    const float* gei = (const float*)d_in[2];
    const float* glr = (const float*)d_in[3];
    const float* gli = (const float*)d_in[4];
    float* out = (float*)d_out;

    float* Hg = (float*)d_ws;    // BB*64*VV floats = 8.4 MB

    k_fused<<<dim3(BB, 8), 512, 0, stream>>>(x, ger, gei, glr, gli, Hg, out);
    k_fixup<<<dim3(BB, 2), 512, 0, stream>>>(x, Hg, out);
}

// Round 23
// 129.000 us; speedup vs baseline: 1.4984x; 1.0227x over previous
//
#include <hip/hip_runtime.h>
#include <math.h>

#define T_LEN 1024
#define VV 512
#define BB 64
#define NB 16
#define ANG_STEP 0.006135923151542565f   // 2*pi/1024
#define FADE_S 487
#define FADE_E 537

typedef float v2f __attribute__((ext_vector_type(2)));   // native vec for nontemporal stores

__device__ constexpr int KB[NB] = {1,2,3,4,5,6,7,8,12,16,24,32,48,64,96,128};
__device__ constexpr float CWT[NB] = {    // cos(2*pi*k/1024)
    0.9999811753f, 0.9999247018f, 0.9998305818f, 0.9996988187f,
    0.9995294175f, 0.9993223846f, 0.9990777278f, 0.9987954562f,
    0.9972904567f, 0.9951847267f, 0.9891765100f, 0.9807852804f,
    0.9569403357f, 0.9238795325f, 0.8314696123f, 0.7071067812f};
__device__ constexpr float SWT[NB] = {    // sin(2*pi*k/1024)
    0.0061358846f, 0.0122715383f, 0.0184067299f, 0.0245412285f,
    0.0306748032f, 0.0368072229f, 0.0429382569f, 0.0490676743f,
    0.0735645636f, 0.0980171403f, 0.1467304745f, 0.1950903220f,
    0.2902846773f, 0.3826834324f, 0.5555702330f, 0.7071067812f};

// ---------------- Kernel A: DFT over a t-half, per (b, 128-v slice) ----------------
// grid (BB, 4, 2) = 512 blocks (2/CU -> 4 waves/SIMD), block 512 = 8 waves.
// Wave w owns t-rows [th*512 + w*64, +64), lane owns v0 = vc*128 + lane*2 (VPT=2).
// cs in registers via rotation recurrence (~4 VALU inst/elem; live ~110 regs).
// 8 wave-partials reduced via stride-17 LDS scr (2 rounds: re, im); block partial
// -> global Xpart[(b*4+vc)*2+th][32 q][128 v]  (q: 0-15 re_j, 16-31 im_j).
__global__ __launch_bounds__(512) void k_dft(const float* __restrict__ x,
                                             float* __restrict__ Xpart) {
    const int b    = blockIdx.x;
    const int vc   = blockIdx.y;          // 0..3
    const int th   = blockIdx.z;          // 0..1
    const int tid  = threadIdx.x;
    const int wave = tid >> 6;            // 0..7
    const int lane = tid & 63;

    __shared__ __align__(16) float scr[4 * 128 * 17];   // 34.8 KB

    const int trow = th * 512 + wave * 64;
    const int v0   = lane * 2;
    const float2* xrd = (const float2*)(x + ((size_t)b * T_LEN + trow) * VV + vc * 128) + lane;

    float ar0[NB], ai0[NB], ar1[NB], ai1[NB], c[NB], s[NB];
#pragma unroll
    for (int j = 0; j < NB; ++j) {
        ar0[j] = ai0[j] = ar1[j] = ai1[j] = 0.f;
        int n0 = (KB[j] * trow) & (T_LEN - 1);
        sincosf(ANG_STEP * (float)n0, &s[j], &c[j]);
    }

#define DFT_STEP(AV)                                            \
    do {                                                        \
        _Pragma("unroll")                                       \
        for (int j = 0; j < NB; ++j) {                          \
            ar0[j] = fmaf((AV).x, c[j], ar0[j]);                \
            ai0[j] = fmaf(-(AV).x, s[j], ai0[j]);               \
            ar1[j] = fmaf((AV).y, c[j], ar1[j]);                \
            ai1[j] = fmaf(-(AV).y, s[j], ai1[j]);               \
            float cn = fmaf(c[j], CWT[j], -(s[j] * SWT[j]));    \
            float sn = fmaf(s[j], CWT[j], c[j] * SWT[j]);       \
            c[j] = cn; s[j] = sn;                               \
        }                                                       \
    } while (0)

    {
        float2 a0 = xrd[(size_t)0 * 256];
        float2 a1 = xrd[(size_t)1 * 256];
        float2 a2 = xrd[(size_t)2 * 256];
        float2 a3 = xrd[(size_t)3 * 256];
#pragma unroll 1
        for (int i = 0; i < 60; i += 4) {
            float2 b0 = xrd[(size_t)(i + 4) * 256];
            float2 b1 = xrd[(size_t)(i + 5) * 256];
            float2 b2 = xrd[(size_t)(i + 6) * 256];
            float2 b3 = xrd[(size_t)(i + 7) * 256];
            DFT_STEP(a0); DFT_STEP(a1); DFT_STEP(a2); DFT_STEP(a3);
            a0 = b0; a1 = b1; a2 = b2; a3 = b3;
        }
        DFT_STEP(a0); DFT_STEP(a1); DFT_STEP(a2); DFT_STEP(a3);
    }
#undef DFT_STEP

    // ---- reduction: 2 rounds (re, im); waves 0-3 write, 4-7 RMW; 4 cells/thread ----
    float Xre[4], Xim[4];

#define RED_ROUND(SRC0, SRC1, DST)                                         \
    do {                                                                   \
        if (wave < 4) {                                                    \
            _Pragma("unroll")                                              \
            for (int j = 0; j < NB; ++j) {                                 \
                scr[((size_t)wave * 128 + v0)     * 17 + j] = SRC0[j];     \
                scr[((size_t)wave * 128 + v0 + 1) * 17 + j] = SRC1[j];     \
            }                                                              \
        }                                                                  \
        __syncthreads();                                                   \
        if (wave >= 4) {                                                   \
            const int w2 = wave - 4;                                       \
            _Pragma("unroll")                                              \
            for (int j = 0; j < NB; ++j) {                                 \
                scr[((size_t)w2 * 128 + v0)     * 17 + j] += SRC0[j];      \
                scr[((size_t)w2 * 128 + v0 + 1) * 17 + j] += SRC1[j];      \
            }                                                              \
        }                                                                  \
        __syncthreads();                                                   \
        _Pragma("unroll")                                                  \
        for (int q = 0; q < 4; ++q) {                                      \
            const int cc = tid * 4 + q;                                    \
            const int vq = cc >> 4, jq = cc & 15;                          \
            DST[q] = scr[((size_t)0 * 128 + vq) * 17 + jq]                 \
                   + scr[((size_t)1 * 128 + vq) * 17 + jq]                 \
                   + scr[((size_t)2 * 128 + vq) * 17 + jq]                 \
                   + scr[((size_t)3 * 128 + vq) * 17 + jq];                \
        }                                                                  \
        __syncthreads();                                                   \
    } while (0)

    RED_ROUND(ar0, ar1, Xre);
    RED_ROUND(ai0, ai1, Xim);
#undef RED_ROUND

    // ---- write block partial (8 values per thread) ----
    float* xp = Xpart + ((size_t)((b * 4 + vc) * 2 + th)) * 32 * 128;
#pragma unroll
    for (int q = 0; q < 4; ++q) {
        const int cc = tid * 4 + q;
        const int vq = cc >> 4, jq = cc & 15;
        xp[(size_t)jq * 128 + vq]        = Xre[q];
        xp[(size_t)(16 + jq) * 128 + vq] = Xim[q];
    }
}

// ---------------- Kernel B: combine partials -> H, then apply over own t-half ----------------
// grid (BB, 4, 2), block 512 = 8 waves. Combine: sum the 2 t-half partials,
// apply gains -> HB[64 q][128 v] in LDS (th=0 also writes Hg for k_fixup).
// Apply: wave w owns t-rows [th*512 + w*64, +64); He for th=0, Hl for th=1
// (fade rows overwritten by k_fixup). x re-read is L3-hot. NT out stores.
__global__ __launch_bounds__(512) void k_comb_apply(const float* __restrict__ x,
                                                    const float* __restrict__ ger,
                                                    const float* __restrict__ gei,
                                                    const float* __restrict__ glr,
                                                    const float* __restrict__ gli,
                                                    const float* __restrict__ Xpart,
                                                    float* __restrict__ Hg,
                                                    float* __restrict__ out) {
    const int b    = blockIdx.x;
    const int vc   = blockIdx.y;
    const int th   = blockIdx.z;
    const int tid  = threadIdx.x;
    const int wave = tid >> 6;
    const int lane = tid & 63;

    __shared__ __align__(16) float HB[64 * 128];   // 32 KB

    // ---- combine + gains: 2048 (j,v) cells, 4 per thread ----
    const float scale = 2.0f / (float)T_LEN;
    {
        const float* xp0 = Xpart + ((size_t)((b * 4 + vc) * 2 + 0)) * 32 * 128;
        const float* xp1 = Xpart + ((size_t)((b * 4 + vc) * 2 + 1)) * 32 * 128;
        float* hg = Hg + (size_t)b * 64 * VV;
#pragma unroll
        for (int k = 0; k < 4; ++k) {
            const int idx = tid + k * 512;       // 0..2047
            const int j = idx >> 7, v = idx & 127;
            const int vg = vc * 128 + v;
            float Xr = xp0[(size_t)j * 128 + v]        + xp1[(size_t)j * 128 + v];
            float Xi = xp0[(size_t)(16 + j) * 128 + v] + xp1[(size_t)(16 + j) * 128 + v];
            float er = ger[vg * NB + j], ei = gei[vg * NB + j];
            float lr = glr[vg * NB + j], li = gli[vg * NB + j];
            float here  = (Xr * er - Xi * ei) * scale;
            float heimN = -(Xr * ei + Xi * er) * scale;
            float hlre  = (Xr * lr - Xi * li) * scale;
            float hlimN = -(Xr * li + Xi * lr) * scale;
            HB[(size_t)j * 128 + v]        = here;
            HB[(size_t)(16 + j) * 128 + v] = heimN;
            HB[(size_t)(32 + j) * 128 + v] = hlre;
            HB[(size_t)(48 + j) * 128 + v] = hlimN;
            if (th == 0) {
                hg[(size_t)j * VV + vg]        = here;
                hg[(size_t)(16 + j) * VV + vg] = heimN;
                hg[(size_t)(32 + j) * VV + vg] = hlre;
                hg[(size_t)(48 + j) * VV + vg] = hlimN;
            }
        }
    }
    __syncthreads();

    // ---- apply over own 64 t-rows ----
    const int trow = th * 512 + wave * 64;
    const int v0   = lane * 2;
    const int qb   = th ? 32 : 0;

    float hr0[NB], hi0[NB], hr1[NB], hi1[NB], c[NB], s[NB];
#pragma unroll
    for (int j = 0; j < NB; ++j) {
        hr0[j] = HB[(size_t)(qb + j) * 128 + v0];
        hr1[j] = HB[(size_t)(qb + j) * 128 + v0 + 1];
        hi0[j] = HB[(size_t)(qb + 16 + j) * 128 + v0];
        hi1[j] = HB[(size_t)(qb + 16 + j) * 128 + v0 + 1];
        int n0 = (KB[j] * trow) & (T_LEN - 1);
        sincosf(ANG_STEP * (float)n0, &s[j], &c[j]);
    }

    const float2* xrd = (const float2*)(x + ((size_t)b * T_LEN + trow) * VV + vc * 128) + lane;
    v2f* ow = (v2f*)(out + ((size_t)b * T_LEN + trow) * VV + vc * 128) + lane;

#define APPLY_STEP(TT, AV)                                      \
    do {                                                        \
        float s0 = 0.f, s1 = 0.f;                               \
        _Pragma("unroll")                                       \
        for (int j = 0; j < NB; ++j) {                          \
            s0 = fmaf(hr0[j], c[j], s0);                        \
            s0 = fmaf(hi0[j], s[j], s0);                        \
            s1 = fmaf(hr1[j], c[j], s1);                        \
            s1 = fmaf(hi1[j], s[j], s1);                        \
            float cn = fmaf(c[j], CWT[j], -(s[j] * SWT[j]));    \
            float sn = fmaf(s[j], CWT[j], c[j] * SWT[j]);       \
            c[j] = cn; s[j] = sn;                               \
        }                                                       \
        v2f ov; ov.x = (AV).x + s0; ov.y = (AV).y + s1;         \
        __builtin_nontemporal_store(ov, &ow[(size_t)(TT) * 256]); \
    } while (0)

    {
        float2 a0 = xrd[(size_t)0 * 256];
        float2 a1 = xrd[(size_t)1 * 256];
        float2 a2 = xrd[(size_t)2 * 256];
        float2 a3 = xrd[(size_t)3 * 256];
#pragma unroll 1
        for (int i = 0; i < 60; i += 4) {
            float2 b0 = xrd[(size_t)(i + 4) * 256];
            float2 b1 = xrd[(size_t)(i + 5) * 256];
            float2 b2 = xrd[(size_t)(i + 6) * 256];
            float2 b3 = xrd[(size_t)(i + 7) * 256];
            APPLY_STEP(i + 0, a0); APPLY_STEP(i + 1, a1);
            APPLY_STEP(i + 2, a2); APPLY_STEP(i + 3, a3);
            a0 = b0; a1 = b1; a2 = b2; a3 = b3;
        }
        APPLY_STEP(60, a0); APPLY_STEP(61, a1);
        APPLY_STEP(62, a2); APPLY_STEP(63, a3);
    }
#undef APPLY_STEP
}

// ---------------- Fade fixup, rows 487..536 only (exact dual-H crossfade) ----------------
// grid (BB, 2), block 512, thread owns v = tid.
__global__ __launch_bounds__(512) void k_fixup(const float* __restrict__ x,
                                               const float* __restrict__ H,
                                               float* __restrict__ out) {
    const int b   = blockIdx.x;
    const int tz  = blockIdx.y;
    const int tid = threadIdx.x;
    const int ts  = tz ? 512 : FADE_S;
    const int te  = tz ? FADE_E : 512;
    const int nt  = te - ts;                   // 25 rows each

    __shared__ float2 tab[32][NB];
    for (int i = tid; i < nt * NB; i += 512) {
        int t = i >> 4, j = i & 15;
        int idx = (KB[j] * (ts + t)) & (T_LEN - 1);
        float ss, cc; sincosf(ANG_STEP * (float)idx, &ss, &cc);
        tab[t][j] = make_float2(cc, ss);
    }

    float er[NB], ei[NB], lr[NB], li[NB];
    const float* hp = H + (size_t)b * 64 * VV + tid;
#pragma unroll
    for (int j = 0; j < NB; ++j) {
        er[j] = hp[(size_t)j        * VV];
        ei[j] = hp[(size_t)(16 + j) * VV];
        lr[j] = hp[(size_t)(32 + j) * VV];
        li[j] = hp[(size_t)(48 + j) * VV];
    }
    __syncthreads();

    const float* xrd = x + ((size_t)b * T_LEN + ts) * VV + tid;
    float*       ow  = out + ((size_t)b * T_LEN + ts) * VV + tid;

    for (int t = 0; t < nt; ++t) {
        float av = xrd[(size_t)t * VV];
        const int tg = ts + t;
        float se = 0.f, sl = 0.f;
#pragma unroll
        for (int j = 0; j < NB; ++j) {
            float2 cs = tab[t][j];
            se = fmaf(er[j], cs.x, se); se = fmaf(ei[j], cs.y, se);
            sl = fmaf(lr[j], cs.x, sl); sl = fmaf(li[j], cs.y, sl);
        }
        float w = 1.0f - (float)(tg - FADE_S) * (1.0f / 50.0f);
        ow[(size_t)t * VV] = av + fmaf(w, se - sl, sl);
    }
}

extern "C" void kernel_launch(void* const* d_in, const int* in_sizes, int n_in,
                              void* d_out, int out_size, void* d_ws, size_t ws_size,
                              hipStream_t stream) {
    (void)in_sizes; (void)n_in; (void)out_size; (void)ws_size;
    const float* x   = (const float*)d_in[0];
    const float* ger = (const float*)d_in[1];
    const float* gei = (const float*)d_in[2];
    const float* glr = (const float*)d_in[3];
    const float* gli = (const float*)d_in[4];
    float* out = (float*)d_out;

    // ws layout: Hg (BB*64*VV floats = 8.4 MB) | Xpart (64*4*2*32*128 floats = 16.8 MB)
    float* Hg    = (float*)d_ws;
    float* Xpart = Hg + (size_t)BB * 64 * VV;

    k_dft<<<dim3(BB, 4, 2), 512, 0, stream>>>(x, Xpart);
    k_comb_apply<<<dim3(BB, 4, 2), 512, 0, stream>>>(x, ger, gei, glr, gli, Xpart, Hg, out);
    k_fixup<<<dim3(BB, 2), 512, 0, stream>>>(x, Hg, out);
}

// Round 24
// 118.287 us; speedup vs baseline: 1.6341x; 1.0906x over previous
//
#include <hip/hip_runtime.h>
#include <math.h>

#define T_LEN 1024
#define VV 512
#define BB 64
#define NB 16
#define ANG_STEP 0.006135923151542565f   // 2*pi/1024
#define FADE_S 487
#define FADE_E 537

typedef float v2f __attribute__((ext_vector_type(2)));   // native vec for nontemporal stores

__device__ constexpr int KB[NB] = {1,2,3,4,5,6,7,8,12,16,24,32,48,64,96,128};
__device__ constexpr float CWT[NB] = {    // cos(2*pi*k/1024)
    0.9999811753f, 0.9999247018f, 0.9998305818f, 0.9996988187f,
    0.9995294175f, 0.9993223846f, 0.9990777278f, 0.9987954562f,
    0.9972904567f, 0.9951847267f, 0.9891765100f, 0.9807852804f,
    0.9569403357f, 0.9238795325f, 0.8314696123f, 0.7071067812f};
__device__ constexpr float SWT[NB] = {    // sin(2*pi*k/1024)
    0.0061358846f, 0.0122715383f, 0.0184067299f, 0.0245412285f,
    0.0306748032f, 0.0368072229f, 0.0429382569f, 0.0490676743f,
    0.0735645636f, 0.0980171403f, 0.1467304745f, 0.1950903220f,
    0.2902846773f, 0.3826834324f, 0.5555702330f, 0.7071067812f};

// ---------------- Fused kernel v9: dual-pipe cs (R17 base + pipe split) ----------------
// grid (BB, 4), block 512 = 8 waves. Wave w owns t-rows [w*128, +128) of the
// block's 128-v slice (lane owns v0 = vc*128 + lane*2, VPT=2).
// Waves 0-3 (t<512): cs from 2-bin-packed LDS table (LDS pipe, ~20.5us/phase).
// Waves 4-7 (t>=512): cs from register rotation recurrence (VALU, ~7us extra).
// Splits the per-t-step cs cost across two independent pipes instead of
// serializing 41us/phase on LDS (R17) or 27us/phase on VALU (R19).
// No sign trick needed: recurrence waves compute true angles.
// Fade rows 487..536 are overwritten by k_fixup afterwards.
__global__ __launch_bounds__(512, 1) void k_fused(const float* __restrict__ x,
                                                  const float* __restrict__ ger,
                                                  const float* __restrict__ gei,
                                                  const float* __restrict__ glr,
                                                  const float* __restrict__ gli,
                                                  float* __restrict__ Hg,
                                                  float* __restrict__ out) {
    const int b    = blockIdx.x;
    const int vc   = blockIdx.y;
    const int tid  = threadIdx.x;
    const int wave = tid >> 6;
    const int lane = tid & 63;

    __shared__ __align__(16) float4 tab4[512][8];            // 64 KB (rows 0..511, waves 0-3)
    __shared__ __align__(16) float  scr[4 * 128 * 17];       // 34 KB reduction scratch

    for (int i = tid; i < 512 * 8; i += 512) {
        int t = i >> 3, m = i & 7;
        int j0 = 2 * m, j1 = 2 * m + 1;
        int idx0 = (KB[j0] * t) & (T_LEN - 1);
        int idx1 = (KB[j1] * t) & (T_LEN - 1);
        float s0, c0, s1, c1;
        sincosf(ANG_STEP * (float)idx0, &s0, &c0);
        sincosf(ANG_STEP * (float)idx1, &s1, &c1);
        tab4[t][m] = make_float4(c0, s0, c1, s1);
    }
    __syncthreads();

    // ---- phase 1: per-wave DFT over its 128 t rows ----
    float ar0[NB], ai0[NB], ar1[NB], ai1[NB];
#pragma unroll
    for (int j = 0; j < NB; ++j) { ar0[j] = ai0[j] = ar1[j] = ai1[j] = 0.f; }

    const int trow = wave * 128;
    const float2* xrd = (const float2*)(x + ((size_t)b * T_LEN + trow) * VV + vc * 128) + lane;

    if (wave < 4) {
        // ---- table path ----
#define DFT_T(TT, AV)                                               \
    do {                                                            \
        _Pragma("unroll")                                           \
        for (int m = 0; m < 8; ++m) {                               \
            float4 cs = tab4[trow + (TT)][m];                       \
            ar0[2*m]   = fmaf((AV).x, cs.x, ar0[2*m]);              \
            ai0[2*m]   = fmaf(-(AV).x, cs.y, ai0[2*m]);             \
            ar1[2*m]   = fmaf((AV).y, cs.x, ar1[2*m]);              \
            ai1[2*m]   = fmaf(-(AV).y, cs.y, ai1[2*m]);             \
            ar0[2*m+1] = fmaf((AV).x, cs.z, ar0[2*m+1]);            \
            ai0[2*m+1] = fmaf(-(AV).x, cs.w, ai0[2*m+1]);           \
            ar1[2*m+1] = fmaf((AV).y, cs.z, ar1[2*m+1]);            \
            ai1[2*m+1] = fmaf(-(AV).y, cs.w, ai1[2*m+1]);           \
        }                                                           \
    } while (0)
        float2 a0 = xrd[(size_t)0 * 256];
        float2 a1 = xrd[(size_t)1 * 256];
        float2 a2 = xrd[(size_t)2 * 256];
        float2 a3 = xrd[(size_t)3 * 256];
        float2 a4 = xrd[(size_t)4 * 256];
        float2 a5 = xrd[(size_t)5 * 256];
        float2 a6 = xrd[(size_t)6 * 256];
        float2 a7 = xrd[(size_t)7 * 256];
#pragma unroll 1
        for (int i = 0; i < 120; i += 8) {
            float2 b0 = xrd[(size_t)(i +  8) * 256];
            float2 b1 = xrd[(size_t)(i +  9) * 256];
            float2 b2 = xrd[(size_t)(i + 10) * 256];
            float2 b3 = xrd[(size_t)(i + 11) * 256];
            float2 b4 = xrd[(size_t)(i + 12) * 256];
            float2 b5 = xrd[(size_t)(i + 13) * 256];
            float2 b6 = xrd[(size_t)(i + 14) * 256];
            float2 b7 = xrd[(size_t)(i + 15) * 256];
            DFT_T(i + 0, a0); DFT_T(i + 1, a1); DFT_T(i + 2, a2); DFT_T(i + 3, a3);
            DFT_T(i + 4, a4); DFT_T(i + 5, a5); DFT_T(i + 6, a6); DFT_T(i + 7, a7);
            a0 = b0; a1 = b1; a2 = b2; a3 = b3;
            a4 = b4; a5 = b5; a6 = b6; a7 = b7;
        }
        DFT_T(120, a0); DFT_T(121, a1); DFT_T(122, a2); DFT_T(123, a3);
        DFT_T(124, a4); DFT_T(125, a5); DFT_T(126, a6); DFT_T(127, a7);
#undef DFT_T
    } else {
        // ---- recurrence path (true angles; no sign trick needed) ----
        float c[NB], s[NB];
#pragma unroll
        for (int j = 0; j < NB; ++j) {
            int n0 = (KB[j] * trow) & (T_LEN - 1);
            sincosf(ANG_STEP * (float)n0, &s[j], &c[j]);
        }
#define DFT_STEP(AV)                                            \
    do {                                                        \
        _Pragma("unroll")                                       \
        for (int j = 0; j < NB; ++j) {                          \
            ar0[j] = fmaf((AV).x, c[j], ar0[j]);                \
            ai0[j] = fmaf(-(AV).x, s[j], ai0[j]);               \
            ar1[j] = fmaf((AV).y, c[j], ar1[j]);                \
            ai1[j] = fmaf(-(AV).y, s[j], ai1[j]);               \
            float cn = fmaf(c[j], CWT[j], -(s[j] * SWT[j]));    \
            float sn = fmaf(s[j], CWT[j], c[j] * SWT[j]);       \
            c[j] = cn; s[j] = sn;                               \
        }                                                       \
    } while (0)
        float2 a0 = xrd[(size_t)0 * 256];
        float2 a1 = xrd[(size_t)1 * 256];
        float2 a2 = xrd[(size_t)2 * 256];
        float2 a3 = xrd[(size_t)3 * 256];
#pragma unroll 1
        for (int i = 0; i < 124; i += 4) {
            float2 b0 = xrd[(size_t)(i + 4) * 256];
            float2 b1 = xrd[(size_t)(i + 5) * 256];
            float2 b2 = xrd[(size_t)(i + 6) * 256];
            float2 b3 = xrd[(size_t)(i + 7) * 256];
            DFT_STEP(a0); DFT_STEP(a1); DFT_STEP(a2); DFT_STEP(a3);
            a0 = b0; a1 = b1; a2 = b2; a3 = b3;
        }
        DFT_STEP(a0); DFT_STEP(a1); DFT_STEP(a2); DFT_STEP(a3);
#undef DFT_STEP
    }
    __syncthreads();

    // ---- reduction: round 1 (re), round 2 (im) ----  (R17-verbatim)
    const int v0 = lane * 2;
    float Xre[4], Xim[4];

    if (wave < 4) {
#pragma unroll
        for (int j = 0; j < NB; ++j) {
            scr[((size_t)wave * 128 + v0)     * 17 + j] = ar0[j];
            scr[((size_t)wave * 128 + v0 + 1) * 17 + j] = ar1[j];
        }
    }
    __syncthreads();
    if (wave >= 4) {
        const int w2 = wave - 4;
#pragma unroll
        for (int j = 0; j < NB; ++j) {
            scr[((size_t)w2 * 128 + v0)     * 17 + j] += ar0[j];
            scr[((size_t)w2 * 128 + v0 + 1) * 17 + j] += ar1[j];
        }
    }
    __syncthreads();
#pragma unroll
    for (int q = 0; q < 4; ++q) {
        const int cc = tid * 4 + q;
        const int vq = cc >> 4, jq = cc & 15;
        Xre[q] = scr[((size_t)0 * 128 + vq) * 17 + jq]
               + scr[((size_t)1 * 128 + vq) * 17 + jq]
               + scr[((size_t)2 * 128 + vq) * 17 + jq]
               + scr[((size_t)3 * 128 + vq) * 17 + jq];
    }
    __syncthreads();

    if (wave < 4) {
#pragma unroll
        for (int j = 0; j < NB; ++j) {
            scr[((size_t)wave * 128 + v0)     * 17 + j] = ai0[j];
            scr[((size_t)wave * 128 + v0 + 1) * 17 + j] = ai1[j];
        }
    }
    __syncthreads();
    if (wave >= 4) {
        const int w2 = wave - 4;
#pragma unroll
        for (int j = 0; j < NB; ++j) {
            scr[((size_t)w2 * 128 + v0)     * 17 + j] += ai0[j];
            scr[((size_t)w2 * 128 + v0 + 1) * 17 + j] += ai1[j];
        }
    }
    __syncthreads();
#pragma unroll
    for (int q = 0; q < 4; ++q) {
        const int cc = tid * 4 + q;
        const int vq = cc >> 4, jq = cc & 15;
        Xim[q] = scr[((size_t)0 * 128 + vq) * 17 + jq]
               + scr[((size_t)1 * 128 + vq) * 17 + jq]
               + scr[((size_t)2 * 128 + vq) * 17 + jq]
               + scr[((size_t)3 * 128 + vq) * 17 + jq];
    }

    // ---- H compute -> global ----  (R17-verbatim)
    const float scale = 2.0f / (float)T_LEN;
    {
        float* hg = Hg + (size_t)b * 64 * VV;
#pragma unroll
        for (int q = 0; q < 4; ++q) {
            const int cc = tid * 4 + q;
            const int vq = cc >> 4, jq = cc & 15;
            const int vg = vc * 128 + vq;
            float er = ger[vg * NB + jq], ei = gei[vg * NB + jq];
            float lr = glr[vg * NB + jq], li = gli[vg * NB + jq];
            float here  = (Xre[q] * er - Xim[q] * ei) * scale;
            float heimN = -(Xre[q] * ei + Xim[q] * er) * scale;
            float hlre  = (Xre[q] * lr - Xim[q] * li) * scale;
            float hlimN = -(Xre[q] * li + Xim[q] * lr) * scale;
            hg[(size_t)jq * VV + vg]        = here;
            hg[(size_t)(16 + jq) * VV + vg] = heimN;
            hg[(size_t)(32 + jq) * VV + vg] = hlre;
            hg[(size_t)(48 + jq) * VV + vg] = hlimN;
        }
    }
    __syncthreads();   // Hg writes visible block-wide before phase-2 reads

    // ---- phase 2: apply (He waves 0..3 via table, Hl waves 4..7 via recurrence) ----
    float hr0[NB], hi0[NB], hr1[NB], hi1[NB];
    {
        const int qb = (wave < 4) ? 0 : 32;
        const float* hgr = Hg + (size_t)b * 64 * VV + vc * 128;
#pragma unroll
        for (int j = 0; j < NB; ++j) {
            hr0[j] = hgr[(size_t)(qb + j) * VV + v0];
            hr1[j] = hgr[(size_t)(qb + j) * VV + v0 + 1];
            hi0[j] = hgr[(size_t)(qb + 16 + j) * VV + v0];
            hi1[j] = hgr[(size_t)(qb + 16 + j) * VV + v0 + 1];
        }
    }

    v2f* ow = (v2f*)(out + ((size_t)b * T_LEN + trow) * VV + vc * 128) + lane;

    if (wave < 4) {
#define APPLY_T(TT, AV)                                                       \
    do {                                                                      \
        float s0 = 0.f, s1 = 0.f;                                             \
        _Pragma("unroll")                                                     \
        for (int m = 0; m < 8; ++m) {                                         \
            float4 cs = tab4[trow + (TT)][m];                                 \
            s0 = fmaf(hr0[2*m], cs.x, s0);   s0 = fmaf(hi0[2*m], cs.y, s0);   \
            s1 = fmaf(hr1[2*m], cs.x, s1);   s1 = fmaf(hi1[2*m], cs.y, s1);   \
            s0 = fmaf(hr0[2*m+1], cs.z, s0); s0 = fmaf(hi0[2*m+1], cs.w, s0); \
            s1 = fmaf(hr1[2*m+1], cs.z, s1); s1 = fmaf(hi1[2*m+1], cs.w, s1); \
        }                                                                     \
        v2f ov; ov.x = (AV).x + s0; ov.y = (AV).y + s1;                       \
        __builtin_nontemporal_store(ov, &ow[(size_t)(TT) * 256]);             \
    } while (0)
        float2 a0 = xrd[(size_t)0 * 256];
        float2 a1 = xrd[(size_t)1 * 256];
        float2 a2 = xrd[(size_t)2 * 256];
        float2 a3 = xrd[(size_t)3 * 256];
        float2 a4 = xrd[(size_t)4 * 256];
        float2 a5 = xrd[(size_t)5 * 256];
        float2 a6 = xrd[(size_t)6 * 256];
        float2 a7 = xrd[(size_t)7 * 256];
#pragma unroll 1
        for (int i = 0; i < 120; i += 8) {
            float2 b0 = xrd[(size_t)(i +  8) * 256];
            float2 b1 = xrd[(size_t)(i +  9) * 256];
            float2 b2 = xrd[(size_t)(i + 10) * 256];
            float2 b3 = xrd[(size_t)(i + 11) * 256];
            float2 b4 = xrd[(size_t)(i + 12) * 256];
            float2 b5 = xrd[(size_t)(i + 13) * 256];
            float2 b6 = xrd[(size_t)(i + 14) * 256];
            float2 b7 = xrd[(size_t)(i + 15) * 256];
            APPLY_T(i + 0, a0); APPLY_T(i + 1, a1); APPLY_T(i + 2, a2); APPLY_T(i + 3, a3);
            APPLY_T(i + 4, a4); APPLY_T(i + 5, a5); APPLY_T(i + 6, a6); APPLY_T(i + 7, a7);
            a0 = b0; a1 = b1; a2 = b2; a3 = b3;
            a4 = b4; a5 = b5; a6 = b6; a7 = b7;
        }
        APPLY_T(120, a0); APPLY_T(121, a1); APPLY_T(122, a2); APPLY_T(123, a3);
        APPLY_T(124, a4); APPLY_T(125, a5); APPLY_T(126, a6); APPLY_T(127, a7);
#undef APPLY_T
    } else {
        float c[NB], s[NB];
#pragma unroll
        for (int j = 0; j < NB; ++j) {
            int n0 = (KB[j] * trow) & (T_LEN - 1);
            sincosf(ANG_STEP * (float)n0, &s[j], &c[j]);
        }
#define APPLY_STEP(TT, AV)                                      \
    do {                                                        \
        float s0 = 0.f, s1 = 0.f;                               \
        _Pragma("unroll")                                       \
        for (int j = 0; j < NB; ++j) {                          \
            s0 = fmaf(hr0[j], c[j], s0);                        \
            s0 = fmaf(hi0[j], s[j], s0);                        \
            s1 = fmaf(hr1[j], c[j], s1);                        \
            s1 = fmaf(hi1[j], s[j], s1);                        \
            float cn = fmaf(c[j], CWT[j], -(s[j] * SWT[j]));    \
            float sn = fmaf(s[j], CWT[j], c[j] * SWT[j]);       \
            c[j] = cn; s[j] = sn;                               \
        }                                                       \
        v2f ov; ov.x = (AV).x + s0; ov.y = (AV).y + s1;         \
        __builtin_nontemporal_store(ov, &ow[(size_t)(TT) * 256]); \
    } while (0)
        float2 a0 = xrd[(size_t)0 * 256];
        float2 a1 = xrd[(size_t)1 * 256];
        float2 a2 = xrd[(size_t)2 * 256];
        float2 a3 = xrd[(size_t)3 * 256];
#pragma unroll 1
        for (int i = 0; i < 124; i += 4) {
            float2 b0 = xrd[(size_t)(i + 4) * 256];
            float2 b1 = xrd[(size_t)(i + 5) * 256];
            float2 b2 = xrd[(size_t)(i + 6) * 256];
            float2 b3 = xrd[(size_t)(i + 7) * 256];
            APPLY_STEP(i + 0, a0); APPLY_STEP(i + 1, a1);
            APPLY_STEP(i + 2, a2); APPLY_STEP(i + 3, a3);
            a0 = b0; a1 = b1; a2 = b2; a3 = b3;
        }
        APPLY_STEP(124, a0); APPLY_STEP(125, a1);
        APPLY_STEP(126, a2); APPLY_STEP(127, a3);
#undef APPLY_STEP
    }
}

// ---------------- Fade fixup, rows 487..536 only (exact dual-H crossfade) ----------------
// grid (BB, 2), block 512, thread owns v = tid.
__global__ __launch_bounds__(512) void k_fixup(const float* __restrict__ x,
                                               const float* __restrict__ H,
                                               float* __restrict__ out) {
    const int b   = blockIdx.x;
    const int tz  = blockIdx.y;
    const int tid = threadIdx.x;
    const int ts  = tz ? 512 : FADE_S;
    const int te  = tz ? FADE_E : 512;
    const int nt  = te - ts;                   // 25 rows each

    __shared__ float2 tab[32][NB];
    for (int i = tid; i < nt * NB; i += 512) {
        int t = i >> 4, j = i & 15;
        int idx = (KB[j] * (ts + t)) & (T_LEN - 1);
        float ss, cc; sincosf(ANG_STEP * (float)idx, &ss, &cc);
        tab[t][j] = make_float2(cc, ss);
    }

    float er[NB], ei[NB], lr[NB], li[NB];
    const float* hp = H + (size_t)b * 64 * VV + tid;
#pragma unroll
    for (int j = 0; j < NB; ++j) {
        er[j] = hp[(size_t)j        * VV];
        ei[j] = hp[(size_t)(16 + j) * VV];
        lr[j] = hp[(size_t)(32 + j) * VV];
        li[j] = hp[(size_t)(48 + j) * VV];
    }
    __syncthreads();

    const float* xrd = x + ((size_t)b * T_LEN + ts) * VV + tid;
    float*       ow  = out + ((size_t)b * T_LEN + ts) * VV + tid;

    for (int t = 0; t < nt; ++t) {
        float av = xrd[(size_t)t * VV];
        const int tg = ts + t;
        float se = 0.f, sl = 0.f;
#pragma unroll
        for (int j = 0; j < NB; ++j) {
            float2 cs = tab[t][j];
            se = fmaf(er[j], cs.x, se); se = fmaf(ei[j], cs.y, se);
            sl = fmaf(lr[j], cs.x, sl); sl = fmaf(li[j], cs.y, sl);
        }
        float w = 1.0f - (float)(tg - FADE_S) * (1.0f / 50.0f);
        ow[(size_t)t * VV] = av + fmaf(w, se - sl, sl);
    }
}

extern "C" void kernel_launch(void* const* d_in, const int* in_sizes, int n_in,
                              void* d_out, int out_size, void* d_ws, size_t ws_size,
                              hipStream_t stream) {
    (void)in_sizes; (void)n_in; (void)out_size; (void)ws_size;
    const float* x   = (const float*)d_in[0];
    const float* ger = (const float*)d_in[1];
    const float* gei = (const float*)d_in[2];
    const float* glr = (const float*)d_in[3];
    const float* gli = (const float*)d_in[4];
    float* out = (float*)d_out;

    float* Hg = (float*)d_ws;    // BB*64*VV floats = 8.4 MB

    k_fused<<<dim3(BB, 4), 512, 0, stream>>>(x, ger, gei, glr, gli, Hg, out);
    k_fixup<<<dim3(BB, 2), 512, 0, stream>>>(x, Hg, out);
}

// Round 25
// 117.002 us; speedup vs baseline: 1.6520x; 1.0110x over previous
//
#include <hip/hip_runtime.h>
#include <math.h>

#define T_LEN 1024
#define VV 512
#define BB 64
#define NB 16
#define ANG_STEP 0.006135923151542565f   // 2*pi/1024
#define FADE_S 487
#define FADE_E 537

typedef short sh8 __attribute__((ext_vector_type(8)));   // 8 bf16 (bit pattern in shorts)
typedef float f4  __attribute__((ext_vector_type(4)));   // MFMA accumulator

__device__ constexpr int KB[NB] = {1,2,3,4,5,6,7,8,12,16,24,32,48,64,96,128};

__device__ inline unsigned short f2bf(float f) {
    union { float f; unsigned u; } x; x.f = f;
    unsigned u = x.u + 0x7FFF + ((x.u >> 16) & 1);   // RNE
    return (unsigned short)(u >> 16);
}
__device__ inline float bf2f(unsigned short h) {
    union { unsigned u; float f; } x; x.u = ((unsigned)h) << 16; return x.f;
}
__device__ inline void store_split(unsigned short* hi, unsigned short* lo, int idx, float f) {
    unsigned short h = f2bf(f);
    hi[idx] = h;
    lo[idx] = f2bf(f - bf2f(h));
}

// ---------------- k_tables: CS1 (DFT A-matrix) and A2 (apply A-matrix), bf16 hi/lo ----------------
// CS1[q][t]: q=2j -> cos(w_j t), q=2j+1 -> -sin(w_j t)   (row-major [32][1024])
// A2[t][q]:  q=2j -> cos(w_j t), q=2j+1 -> +sin(w_j t)   (row-major [1024][32])
__global__ __launch_bounds__(256) void k_tables(unsigned short* __restrict__ CS1hi,
                                                unsigned short* __restrict__ CS1lo,
                                                unsigned short* __restrict__ A2hi,
                                                unsigned short* __restrict__ A2lo) {
    int idx = blockIdx.x * 256 + threadIdx.x;   // 0..32767
    int q = idx & 31, t = idx >> 5;
    int j = q >> 1;
    int a = (KB[j] * t) & (T_LEN - 1);
    float ss, cc; sincosf(ANG_STEP * (float)a, &ss, &cc);
    float cs1 = (q & 1) ? -ss : cc;
    float a2  = (q & 1) ?  ss : cc;
    store_split(CS1hi, CS1lo, q * 1024 + t, cs1);
    store_split(A2hi,  A2lo,  t * 32 + q,  a2);
}

// ---------------- k_mfma: fused DFT-GEMM + combine + apply-GEMM ----------------
// grid (BB, 8): block owns (b, 64-v slice at v0=vc*64). block 256 = 4 waves;
// wave w owns N-tile v0 + w*16.
// Pass 1: X[32,512] = CS1[32,1024] x[1024,512]  (per b), K staged 32 rows at a
//   time into LDS as bf16 hi/lo transposed [v][t]. 3 split-products share one
//   fp32 accumulator (hi*hi + hi*lo + lo*hi; lo*lo ~2^-18, dropped).
// Combine: lane holds (Xre_j, Xim_j) pairs in its C-regs (rows 2j,2j+1 land in
//   regs 2p,2p+1 of the same lane); apply gains -> H2{e,l} bf16 hi/lo in LDS
//   (B-matrix layout [v][q]) + fp32 Hg for k_fixup.
// Pass 2: out[t,v] = x[t,v] + A2[t,32]·H2[32,v]; He rows t<512, Hl t>=512.
// Fragment layouts: A row=lane%16, k=(lane>>4)*8+i; B col=lane%16, same k;
// C col=lane&15, row=(lane>>4)*4+reg (m89-verified).
__global__ __launch_bounds__(256, 2) void k_mfma(const float* __restrict__ x,
                                                 const float* __restrict__ ger,
                                                 const float* __restrict__ gei,
                                                 const float* __restrict__ glr,
                                                 const float* __restrict__ gli,
                                                 const unsigned short* __restrict__ CS1hi,
                                                 const unsigned short* __restrict__ CS1lo,
                                                 const unsigned short* __restrict__ A2hi,
                                                 const unsigned short* __restrict__ A2lo,
                                                 float* __restrict__ Hg,
                                                 float* __restrict__ out) {
    const int b    = blockIdx.x;
    const int vc   = blockIdx.y;
    const int tid  = threadIdx.x;
    const int wave = tid >> 6;
    const int l    = tid & 63;
    const int v0   = vc * 64;

    // row stride 40 ushorts = 80 B: 16B-aligned rows, 8-bank spread (2-way, free)
    __shared__ __align__(16) unsigned short xthi[64 * 40], xtlo[64 * 40];
    __shared__ __align__(16) unsigned short Hehi[64 * 40], Helo[64 * 40];
    __shared__ __align__(16) unsigned short Hlhi[64 * 40], Hllo[64 * 40];

    const int vl = tid & 63;          // staging: v within slice
    const int tq = tid >> 6;          // staging: t-subchunk
    const int lr16 = l & 15;          // fragment row/col within tile
    const int kg   = l >> 4;          // k-group 0..3
    const int nrow = wave * 16 + lr16;
    const int vglob = v0 + nrow;

    f4 acc0 = {0.f, 0.f, 0.f, 0.f};
    f4 acc1 = {0.f, 0.f, 0.f, 0.f};

    // ---- pass 1: K-loop over 32 t-blocks of 32 ----
    for (int tb = 0; tb < 32; ++tb) {
        __syncthreads();
        // stage x[tb*32 .. +32][v0 .. +64] -> bf16 hi/lo transposed [v][t_local]
        {
            const float* xp = x + ((size_t)(b * T_LEN + tb * 32 + tq * 8)) * VV + v0 + vl;
            float vals[8];
#pragma unroll
            for (int i = 0; i < 8; ++i) vals[i] = xp[(size_t)i * VV];
            sh8 phi, plo;
#pragma unroll
            for (int i = 0; i < 8; ++i) {
                unsigned short h = f2bf(vals[i]);
                phi[i] = (short)h;
                plo[i] = (short)f2bf(vals[i] - bf2f(h));
            }
            *(sh8*)&xthi[vl * 40 + tq * 8] = phi;
            *(sh8*)&xtlo[vl * 40 + tq * 8] = plo;
        }
        __syncthreads();

        const int kb = tb * 32 + kg * 8;
        sh8 aH0 = *(const sh8*)&CS1hi[(size_t)lr16 * 1024 + kb];
        sh8 aH1 = *(const sh8*)&CS1hi[(size_t)(lr16 + 16) * 1024 + kb];
        sh8 aL0 = *(const sh8*)&CS1lo[(size_t)lr16 * 1024 + kb];
        sh8 aL1 = *(const sh8*)&CS1lo[(size_t)(lr16 + 16) * 1024 + kb];
        sh8 bH  = *(const sh8*)&xthi[nrow * 40 + kg * 8];
        sh8 bL  = *(const sh8*)&xtlo[nrow * 40 + kg * 8];

        acc0 = __builtin_amdgcn_mfma_f32_16x16x32_bf16(aH0, bH, acc0, 0, 0, 0);
        acc0 = __builtin_amdgcn_mfma_f32_16x16x32_bf16(aH0, bL, acc0, 0, 0, 0);
        acc0 = __builtin_amdgcn_mfma_f32_16x16x32_bf16(aL0, bH, acc0, 0, 0, 0);
        acc1 = __builtin_amdgcn_mfma_f32_16x16x32_bf16(aH1, bH, acc1, 0, 0, 0);
        acc1 = __builtin_amdgcn_mfma_f32_16x16x32_bf16(aH1, bL, acc1, 0, 0, 0);
        acc1 = __builtin_amdgcn_mfma_f32_16x16x32_bf16(aL1, bH, acc1, 0, 0, 0);
    }

    // ---- combine: acc -> H2{e,l} (LDS bf16 hi/lo) + Hg (global fp32) ----
    {
        const float scale = 2.0f / (float)T_LEN;
        float* hg = Hg + (size_t)b * 64 * VV;
#pragma unroll
        for (int m = 0; m < 2; ++m) {
            f4 acc = m ? acc1 : acc0;
#pragma unroll
            for (int p = 0; p < 2; ++p) {
                const int j  = (l >> 4) * 2 + p + 8 * m;
                const float Xr = acc[2 * p];
                const float Xi = acc[2 * p + 1];
                float er = ger[vglob * NB + j], ei = gei[vglob * NB + j];
                float lrg = glr[vglob * NB + j], lig = gli[vglob * NB + j];
                float h2ec = scale * (Xr * er - Xi * ei);
                float h2es = -scale * (Xr * ei + Xi * er);
                float h2lc = scale * (Xr * lrg - Xi * lig);
                float h2ls = -scale * (Xr * lig + Xi * lrg);
                hg[(size_t)j * VV + vglob]        = h2ec;
                hg[(size_t)(16 + j) * VV + vglob] = h2es;
                hg[(size_t)(32 + j) * VV + vglob] = h2lc;
                hg[(size_t)(48 + j) * VV + vglob] = h2ls;
                const int q0 = 2 * j, q1 = 2 * j + 1;
                store_split(Hehi, Helo, nrow * 40 + q0, h2ec);
                store_split(Hehi, Helo, nrow * 40 + q1, h2es);
                store_split(Hlhi, Hllo, nrow * 40 + q0, h2lc);
                store_split(Hlhi, Hllo, nrow * 40 + q1, h2ls);
            }
        }
    }
    __syncthreads();

    // ---- pass 2: out = x + A2 * H2 ----
    sh8 BeH = *(const sh8*)&Hehi[nrow * 40 + kg * 8];
    sh8 BeL = *(const sh8*)&Helo[nrow * 40 + kg * 8];
    sh8 BlH = *(const sh8*)&Hlhi[nrow * 40 + kg * 8];
    sh8 BlL = *(const sh8*)&Hllo[nrow * 40 + kg * 8];

#pragma unroll 2
    for (int mt = 0; mt < 64; ++mt) {
        const int t0 = mt * 16;
        sh8 a2H = *(const sh8*)&A2hi[(size_t)(t0 + lr16) * 32 + kg * 8];
        sh8 a2L = *(const sh8*)&A2lo[(size_t)(t0 + lr16) * 32 + kg * 8];
        sh8 bH = (mt < 32) ? BeH : BlH;
        sh8 bL = (mt < 32) ? BeL : BlL;
        f4 acc = {0.f, 0.f, 0.f, 0.f};
        acc = __builtin_amdgcn_mfma_f32_16x16x32_bf16(a2H, bH, acc, 0, 0, 0);
        acc = __builtin_amdgcn_mfma_f32_16x16x32_bf16(a2H, bL, acc, 0, 0, 0);
        acc = __builtin_amdgcn_mfma_f32_16x16x32_bf16(a2L, bH, acc, 0, 0, 0);
#pragma unroll
        for (int reg = 0; reg < 4; ++reg) {
            const int t = t0 + (l >> 4) * 4 + reg;
            const size_t off = ((size_t)(b * T_LEN + t)) * VV + vglob;
            float val = x[off] + acc[reg];
            __builtin_nontemporal_store(val, &out[off]);
        }
    }
}

// ---------------- Fade fixup, rows 487..536 only (exact dual-H crossfade) ----------------
// grid (BB, 2), block 512, thread owns v = tid.
__global__ __launch_bounds__(512) void k_fixup(const float* __restrict__ x,
                                               const float* __restrict__ H,
                                               float* __restrict__ out) {
    const int b   = blockIdx.x;
    const int tz  = blockIdx.y;
    const int tid = threadIdx.x;
    const int ts  = tz ? 512 : FADE_S;
    const int te  = tz ? FADE_E : 512;
    const int nt  = te - ts;                   // 25 rows each

    __shared__ float2 tab[32][NB];
    for (int i = tid; i < nt * NB; i += 512) {
        int t = i >> 4, j = i & 15;
        int idx = (KB[j] * (ts + t)) & (T_LEN - 1);
        float ss, cc; sincosf(ANG_STEP * (float)idx, &ss, &cc);
        tab[t][j] = make_float2(cc, ss);
    }

    float er[NB], ei[NB], lr[NB], li[NB];
    const float* hp = H + (size_t)b * 64 * VV + tid;
#pragma unroll
    for (int j = 0; j < NB; ++j) {
        er[j] = hp[(size_t)j        * VV];
        ei[j] = hp[(size_t)(16 + j) * VV];
        lr[j] = hp[(size_t)(32 + j) * VV];
        li[j] = hp[(size_t)(48 + j) * VV];
    }
    __syncthreads();

    const float* xrd = x + ((size_t)b * T_LEN + ts) * VV + tid;
    float*       ow  = out + ((size_t)b * T_LEN + ts) * VV + tid;

    for (int t = 0; t < nt; ++t) {
        float av = xrd[(size_t)t * VV];
        const int tg = ts + t;
        float se = 0.f, sl = 0.f;
#pragma unroll
        for (int j = 0; j < NB; ++j) {
            float2 cs = tab[t][j];
            se = fmaf(er[j], cs.x, se); se = fmaf(ei[j], cs.y, se);
            sl = fmaf(lr[j], cs.x, sl); sl = fmaf(li[j], cs.y, sl);
        }
        float w = 1.0f - (float)(tg - FADE_S) * (1.0f / 50.0f);
        ow[(size_t)t * VV] = av + fmaf(w, se - sl, sl);
    }
}

extern "C" void kernel_launch(void* const* d_in, const int* in_sizes, int n_in,
                              void* d_out, int out_size, void* d_ws, size_t ws_size,
                              hipStream_t stream) {
    (void)in_sizes; (void)n_in; (void)out_size; (void)ws_size;
    const float* x   = (const float*)d_in[0];
    const float* ger = (const float*)d_in[1];
    const float* gei = (const float*)d_in[2];
    const float* glr = (const float*)d_in[3];
    const float* gli = (const float*)d_in[4];
    float* out = (float*)d_out;

    // ws: 4 bf16 tables (32768 ushorts each = 256 KB total) | Hg (8.4 MB fp32)
    unsigned short* CS1hi = (unsigned short*)d_ws;
    unsigned short* CS1lo = CS1hi + 32 * 1024;
    unsigned short* A2hi  = CS1lo + 32 * 1024;
    unsigned short* A2lo  = A2hi + 32 * 1024;
    float* Hg = (float*)(A2lo + 32 * 1024);

    k_tables<<<dim3(128), 256, 0, stream>>>(CS1hi, CS1lo, A2hi, A2lo);
    k_mfma<<<dim3(BB, 8), 256, 0, stream>>>(x, ger, gei, glr, gli,
                                            CS1hi, CS1lo, A2hi, A2lo, Hg, out);
    k_fixup<<<dim3(BB, 2), 512, 0, stream>>>(x, Hg, out);
}